// Round 1
// baseline (295.542 us; speedup 1.0000x reference)
//
#include <hip/hip_runtime.h>
#include <hip/hip_bf16.h>

typedef __attribute__((ext_vector_type(4))) float  f32x4;
typedef __bf16 bf16x8 __attribute__((ext_vector_type(8)));

#define MFMA_16x16x32(a, b, c) __builtin_amdgcn_mfma_f32_16x16x32_bf16((a), (b), (c), 0, 0, 0)

// Problem constants
// B=2, S=2048, D=1024, H=16, HD=64; BH = 32 head-batches; tokens = 4096.

// ---------------------------------------------------------------------------
// Kernel 1: QKV projection. Y = X @ W^T + b, output bf16 in [bh][s][64].
// Tile 128x128, BK=32, 4 waves (2x2), each wave 64x64 (4x4 frags of 16x16).
// fp32 -> bf16 conversion fused into the LDS staging.
// z = 0/1/2 -> Q/K/V. Q additionally scaled by 0.125 (1/sqrt(64)).
// ---------------------------------------------------------------------------
__global__ __launch_bounds__(256) void qkv_gemm(
    const float* __restrict__ X,
    const float* __restrict__ Wq, const float* __restrict__ bq,
    const float* __restrict__ Wk, const float* __restrict__ bk,
    const float* __restrict__ Wv, const float* __restrict__ bv,
    __bf16* __restrict__ Qb, __bf16* __restrict__ Kb, __bf16* __restrict__ Vb)
{
    const int z = blockIdx.z;
    const float* W    = (z == 0) ? Wq : (z == 1) ? Wk : Wv;
    const float* bias = (z == 0) ? bq : (z == 1) ? bk : bv;
    __bf16* Ob        = (z == 0) ? Qb : (z == 1) ? Kb : Vb;
    const float oscale = (z == 0) ? 0.125f : 1.0f;

    const int row0 = blockIdx.x * 128;   // token dim (M)
    const int col0 = blockIdx.y * 128;   // e dim (N)

    __shared__ __align__(16) __bf16 As[128 * 32];
    __shared__ __align__(16) __bf16 Bs[128 * 32];

    const int t    = threadIdx.x;
    const int lane = t & 63;
    const int w    = t >> 6;
    const int wr   = w >> 1, wc = w & 1;
    const int l15  = lane & 15, g = lane >> 4;

    f32x4 zero = {0.f, 0.f, 0.f, 0.f};
    f32x4 acc[4][4];
    #pragma unroll
    for (int m = 0; m < 4; ++m)
        #pragma unroll
        for (int n = 0; n < 4; ++n) acc[m][n] = zero;

    // staging assignment: 2 threads per row, 16 fp32 each
    const int srow = t >> 1;             // 0..127
    const int scol = (t & 1) * 16;       // 0 or 16
    const float* ga = X + (size_t)(row0 + srow) * 1024 + scol;
    const float* gb = W + (size_t)(col0 + srow) * 1024 + scol;
    __bf16* la = As + srow * 32 + scol;
    __bf16* lb = Bs + srow * 32 + scol;

    for (int k0 = 0; k0 < 1024; k0 += 32) {
        f32x4 av[4], bw[4];
        #pragma unroll
        for (int q = 0; q < 4; ++q) av[q] = *reinterpret_cast<const f32x4*>(ga + k0 + q * 4);
        #pragma unroll
        for (int q = 0; q < 4; ++q) bw[q] = *reinterpret_cast<const f32x4*>(gb + k0 + q * 4);

        __syncthreads();   // protect previous iteration's fragment reads

        bf16x8 pa0, pa1, pb0, pb1;
        #pragma unroll
        for (int j = 0; j < 4; ++j) {
            pa0[j] = (__bf16)av[0][j];  pa0[4 + j] = (__bf16)av[1][j];
            pa1[j] = (__bf16)av[2][j];  pa1[4 + j] = (__bf16)av[3][j];
            pb0[j] = (__bf16)bw[0][j];  pb0[4 + j] = (__bf16)bw[1][j];
            pb1[j] = (__bf16)bw[2][j];  pb1[4 + j] = (__bf16)bw[3][j];
        }
        *reinterpret_cast<bf16x8*>(la)     = pa0;
        *reinterpret_cast<bf16x8*>(la + 8) = pa1;
        *reinterpret_cast<bf16x8*>(lb)     = pb0;
        *reinterpret_cast<bf16x8*>(lb + 8) = pb1;

        __syncthreads();

        bf16x8 af[4], bf[4];
        const int kk = g * 8;
        #pragma unroll
        for (int m = 0; m < 4; ++m)
            af[m] = *reinterpret_cast<const bf16x8*>(As + (wr * 64 + m * 16 + l15) * 32 + kk);
        #pragma unroll
        for (int n = 0; n < 4; ++n)
            bf[n] = *reinterpret_cast<const bf16x8*>(Bs + (wc * 64 + n * 16 + l15) * 32 + kk);

        #pragma unroll
        for (int m = 0; m < 4; ++m)
            #pragma unroll
            for (int n = 0; n < 4; ++n)
                acc[m][n] = MFMA_16x16x32(af[m], bf[n], acc[m][n]);
    }

    // epilogue: C[row=(g*4+j), col=l15] per 16x16 frag (verified m89 layout)
    #pragma unroll
    for (int n = 0; n < 4; ++n) {
        const int e  = col0 + wc * 64 + n * 16 + l15;
        const float bv_ = bias[e];
        const int h = e >> 6, hd = e & 63;
        #pragma unroll
        for (int m = 0; m < 4; ++m) {
            #pragma unroll
            for (int j = 0; j < 4; ++j) {
                const int tok = row0 + wr * 64 + m * 16 + g * 4 + j;
                const int b = tok >> 11, s = tok & 2047;
                const int bh = b * 16 + h;
                Ob[((size_t)(bh * 2048 + s) << 6) | hd] =
                    (__bf16)((acc[m][n][j] + bv_) * oscale);
            }
        }
    }
}

// ---------------------------------------------------------------------------
// Kernel 2: V [bh][s][64] -> Vt [bh][64][s]  (64x64 LDS tile transpose)
// ---------------------------------------------------------------------------
__global__ __launch_bounds__(256) void v_transpose(
    const __bf16* __restrict__ V, __bf16* __restrict__ Vt)
{
    __shared__ __align__(16) __bf16 T[64 * 72];   // stride 72 keeps 16B alignment
    const int t  = threadIdx.x;
    const int bh = blockIdx.y;
    const int s0 = blockIdx.x * 64;
    const int r  = t >> 2, q = t & 3;

    const __bf16* src = V + ((size_t)(bh * 2048 + s0 + r) << 6) + q * 16;
    bf16x8 v0 = *reinterpret_cast<const bf16x8*>(src);
    bf16x8 v1 = *reinterpret_cast<const bf16x8*>(src + 8);
    #pragma unroll
    for (int i = 0; i < 8; ++i) {
        T[(q * 16 + i) * 72 + r]     = v0[i];
        T[(q * 16 + 8 + i) * 72 + r] = v1[i];
    }
    __syncthreads();
    const int d = r, sc = q * 16;
    bf16x8 o0 = *reinterpret_cast<const bf16x8*>(&T[d * 72 + sc]);
    bf16x8 o1 = *reinterpret_cast<const bf16x8*>(&T[d * 72 + sc + 8]);
    __bf16* dst = Vt + ((size_t)(bh * 64 + d) << 11) + s0 + sc;
    *reinterpret_cast<bf16x8*>(dst)     = o0;
    *reinterpret_cast<bf16x8*>(dst + 8) = o1;
}

// ---------------------------------------------------------------------------
// Kernel 3: flash attention. Block = 4 independent waves, wave = 16 q rows.
// KV tiles of 64 read directly from global (L2/L3-resident).
// Scores in C-layout; softmax reduce over lane&15 groups; P through per-wave
// LDS to become the PV A-operand. Scale (0.125) pre-folded into Q.
// ---------------------------------------------------------------------------
__global__ __launch_bounds__(256) void flash_attn(
    const __bf16* __restrict__ Qb, const __bf16* __restrict__ Kb,
    const __bf16* __restrict__ Vt, const float* __restrict__ mask,
    float* __restrict__ out)
{
    const int qt = blockIdx.x;       // q tile (64 rows)
    const int bh = blockIdx.y;       // b*16 + h
    const int b  = bh >> 4;
    const int h  = bh & 15;
    const int t  = threadIdx.x;
    const int lane = t & 63;
    const int w  = t >> 6;
    const int l15 = lane & 15, g = lane >> 4;
    const int q0 = qt * 64 + w * 16;

    __shared__ __align__(16) __bf16 P[4][1024];   // per-wave 16x64 P tile

    bf16x8 aq[2];
    {
        const __bf16* qp = Qb + ((size_t)(bh * 2048 + q0 + l15) << 6) + g * 8;
        aq[0] = *reinterpret_cast<const bf16x8*>(qp);
        aq[1] = *reinterpret_cast<const bf16x8*>(qp + 32);
    }

    f32x4 zero = {0.f, 0.f, 0.f, 0.f};
    f32x4 o[4];
    #pragma unroll
    for (int i = 0; i < 4; ++i) o[i] = zero;
    float mrun[4], lrun[4];
    #pragma unroll
    for (int j = 0; j < 4; ++j) { mrun[j] = -INFINITY; lrun[j] = 0.f; }

    const float* maskb = mask + b * 2048;

    for (int kt = 0; kt < 32; ++kt) {
        const int kbase = kt * 64;

        // ---- QK^T: scores[16 q][64 k], 4 frags of 16x16, K-dim=64 in 2 MFMAs
        f32x4 sc[4];
        #pragma unroll
        for (int f = 0; f < 4; ++f) {
            const __bf16* kp = Kb + ((size_t)(bh * 2048 + kbase + f * 16 + l15) << 6) + g * 8;
            bf16x8 bk0 = *reinterpret_cast<const bf16x8*>(kp);
            bf16x8 bk1 = *reinterpret_cast<const bf16x8*>(kp + 32);
            f32x4 s = MFMA_16x16x32(aq[0], bk0, zero);
            s = MFMA_16x16x32(aq[1], bk1, s);
            s += maskb[kbase + f * 16 + l15];   // additive mask (broadcast rows)
            sc[f] = s;
        }

        // ---- online softmax (row r = g*4+j; reduce over lane&15)
        float sf[4], rsum[4];
        #pragma unroll
        for (int j = 0; j < 4; ++j) {
            float tj = fmaxf(fmaxf(sc[0][j], sc[1][j]), fmaxf(sc[2][j], sc[3][j]));
            #pragma unroll
            for (int d_ = 1; d_ < 16; d_ <<= 1) tj = fmaxf(tj, __shfl_xor(tj, d_));
            const float mn = fmaxf(mrun[j], tj);
            sf[j] = __expf(mrun[j] - mn);
            mrun[j] = mn;
            rsum[j] = 0.f;
        }
        #pragma unroll
        for (int f = 0; f < 4; ++f)
            #pragma unroll
            for (int j = 0; j < 4; ++j) {
                const float p = __expf(sc[f][j] - mrun[j]);
                sc[f][j] = p;
                rsum[j] += p;
            }
        #pragma unroll
        for (int j = 0; j < 4; ++j) {
            float rs = rsum[j];
            #pragma unroll
            for (int d_ = 1; d_ < 16; d_ <<= 1) rs += __shfl_xor(rs, d_);
            lrun[j] = lrun[j] * sf[j] + rs;
        }
        #pragma unroll
        for (int fd = 0; fd < 4; ++fd)
            #pragma unroll
            for (int j = 0; j < 4; ++j) o[fd][j] *= sf[j];

        // ---- P (C-layout) -> LDS -> A-operand layout. Per-wave buffer, the
        // wave executes in lockstep and the compiler orders ds ops (may-alias),
        // so no block barrier is needed.
        #pragma unroll
        for (int f = 0; f < 4; ++f)
            #pragma unroll
            for (int j = 0; j < 4; ++j)
                P[w][(g * 4 + j) * 64 + f * 16 + l15] = (__bf16)sc[f][j];

        bf16x8 pa0 = *reinterpret_cast<const bf16x8*>(&P[w][l15 * 64 + g * 8]);
        bf16x8 pa1 = *reinterpret_cast<const bf16x8*>(&P[w][l15 * 64 + 32 + g * 8]);

        // ---- PV: ctx[16 q][64 d] += P[16x64] * V[64x64]; B-operand from Vt
        #pragma unroll
        for (int fd = 0; fd < 4; ++fd) {
            const __bf16* vp = Vt + ((size_t)(bh * 64 + fd * 16 + l15) << 11) + kbase + g * 8;
            bf16x8 bv0 = *reinterpret_cast<const bf16x8*>(vp);
            bf16x8 bv1 = *reinterpret_cast<const bf16x8*>(vp + 32);
            o[fd] = MFMA_16x16x32(pa0, bv0, o[fd]);
            o[fd] = MFMA_16x16x32(pa1, bv1, o[fd]);
        }
    }

    // ---- epilogue: out fp32 [b][s][1024]
    #pragma unroll
    for (int j = 0; j < 4; ++j) {
        const int s = q0 + g * 4 + j;
        const float inv = 1.0f / lrun[j];
        float* op = out + ((size_t)(b * 2048 + s) << 10) + h * 64;
        #pragma unroll
        for (int fd = 0; fd < 4; ++fd)
            op[fd * 16 + l15] = o[fd][j] * inv;
    }
}

// ---------------------------------------------------------------------------
extern "C" void kernel_launch(void* const* d_in, const int* in_sizes, int n_in,
                              void* d_out, int out_size, void* d_ws, size_t ws_size,
                              hipStream_t stream)
{
    const float* X    = (const float*)d_in[0];
    const float* mask = (const float*)d_in[1];
    const float* Wq   = (const float*)d_in[2];
    const float* bq   = (const float*)d_in[3];
    const float* Wk   = (const float*)d_in[4];
    const float* bk   = (const float*)d_in[5];
    const float* Wv   = (const float*)d_in[6];
    const float* bv   = (const float*)d_in[7];
    float* out = (float*)d_out;

    const size_t HEADS_ELEMS = (size_t)32 * 2048 * 64;   // 4 Mi elems
    __bf16* Qb = (__bf16*)d_ws;
    __bf16* Kb = Qb + HEADS_ELEMS;
    __bf16* Vb = Kb + HEADS_ELEMS;
    __bf16* Vt = Vb + HEADS_ELEMS;

    qkv_gemm<<<dim3(32, 8, 3), 256, 0, stream>>>(X, Wq, bq, Wk, bk, Wv, bv, Qb, Kb, Vb);
    v_transpose<<<dim3(32, 32), 256, 0, stream>>>(Vb, Vt);
    flash_attn<<<dim3(32, 32), 256, 0, stream>>>(Qb, Kb, Vt, mask, out);
}

// Round 2
// 196.497 us; speedup vs baseline: 1.5041x; 1.5041x over previous
//
#include <hip/hip_runtime.h>
#include <hip/hip_bf16.h>

typedef __attribute__((ext_vector_type(4)))  float f32x4;
typedef __attribute__((ext_vector_type(16))) float f32x16;
typedef __bf16 bf16x8 __attribute__((ext_vector_type(8)));
typedef __attribute__((ext_vector_type(4))) unsigned int u32x4;

#define MFMA16(a, b, c) __builtin_amdgcn_mfma_f32_16x16x32_bf16((a), (b), (c), 0, 0, 0)
#define MFMA32(a, b, c) __builtin_amdgcn_mfma_f32_32x32x16_bf16((a), (b), (c), 0, 0, 0)

#define LOG2E 1.4426950408889634f

static __device__ inline f32x16 f16zero() {
    f32x16 v;
    #pragma unroll
    for (int i = 0; i < 16; ++i) v[i] = 0.f;
    return v;
}

// pack two f32 -> bf16x2 in a u32 (compiler emits cvt_pk / v_perm)
static __device__ inline unsigned pk2(float a, float b) {
    unsigned short ua = __builtin_bit_cast(unsigned short, (__bf16)a);
    unsigned short ub = __builtin_bit_cast(unsigned short, (__bf16)b);
    return (unsigned)ua | ((unsigned)ub << 16);
}

// v_permlane32_swap_b32: x' = {x_low, y_low}, y' = {x_high, y_high}
static __device__ inline void plswap(unsigned& x, unsigned& y) {
#if __has_builtin(__builtin_amdgcn_permlane32_swap)
    auto r = __builtin_amdgcn_permlane32_swap((int)x, (int)y, false, false);
    x = (unsigned)r[0];
    y = (unsigned)r[1];
#else
    unsigned ox = (unsigned)__shfl_xor((int)x, 32);
    unsigned oy = (unsigned)__shfl_xor((int)y, 32);
    const bool lo = ((threadIdx.x & 63) < 32);
    unsigned nx = lo ? x : oy;
    unsigned ny = lo ? ox : y;
    x = nx; y = ny;
#endif
}

// ---------------------------------------------------------------------------
// Kernel 1: QKV projection. Y = X @ W^T + b, output bf16 in [bh][s][64].
// Q additionally scaled by 0.125*log2e (score scale folded + exp2 domain).
// ---------------------------------------------------------------------------
__global__ __launch_bounds__(256) void qkv_gemm(
    const float* __restrict__ X,
    const float* __restrict__ Wq, const float* __restrict__ bq,
    const float* __restrict__ Wk, const float* __restrict__ bk,
    const float* __restrict__ Wv, const float* __restrict__ bv,
    __bf16* __restrict__ Qb, __bf16* __restrict__ Kb, __bf16* __restrict__ Vb)
{
    const int z = blockIdx.z;
    const float* W    = (z == 0) ? Wq : (z == 1) ? Wk : Wv;
    const float* bias = (z == 0) ? bq : (z == 1) ? bk : bv;
    __bf16* Ob        = (z == 0) ? Qb : (z == 1) ? Kb : Vb;
    const float oscale = (z == 0) ? (0.125f * LOG2E) : 1.0f;

    const int row0 = blockIdx.x * 128;   // token dim (M)
    const int col0 = blockIdx.y * 128;   // e dim (N)

    __shared__ __align__(16) __bf16 As[128 * 32];
    __shared__ __align__(16) __bf16 Bs[128 * 32];

    const int t    = threadIdx.x;
    const int lane = t & 63;
    const int w    = t >> 6;
    const int wr   = w >> 1, wc = w & 1;
    const int l15  = lane & 15, g = lane >> 4;

    f32x4 zero = {0.f, 0.f, 0.f, 0.f};
    f32x4 acc[4][4];
    #pragma unroll
    for (int m = 0; m < 4; ++m)
        #pragma unroll
        for (int n = 0; n < 4; ++n) acc[m][n] = zero;

    const int srow = t >> 1;
    const int scol = (t & 1) * 16;
    const float* ga = X + (size_t)(row0 + srow) * 1024 + scol;
    const float* gb = W + (size_t)(col0 + srow) * 1024 + scol;
    __bf16* la = As + srow * 32 + scol;
    __bf16* lb = Bs + srow * 32 + scol;

    for (int k0 = 0; k0 < 1024; k0 += 32) {
        f32x4 av[4], bw[4];
        #pragma unroll
        for (int q = 0; q < 4; ++q) av[q] = *reinterpret_cast<const f32x4*>(ga + k0 + q * 4);
        #pragma unroll
        for (int q = 0; q < 4; ++q) bw[q] = *reinterpret_cast<const f32x4*>(gb + k0 + q * 4);

        __syncthreads();

        bf16x8 pa0, pa1, pb0, pb1;
        #pragma unroll
        for (int j = 0; j < 4; ++j) {
            pa0[j] = (__bf16)av[0][j];  pa0[4 + j] = (__bf16)av[1][j];
            pa1[j] = (__bf16)av[2][j];  pa1[4 + j] = (__bf16)av[3][j];
            pb0[j] = (__bf16)bw[0][j];  pb0[4 + j] = (__bf16)bw[1][j];
            pb1[j] = (__bf16)bw[2][j];  pb1[4 + j] = (__bf16)bw[3][j];
        }
        *reinterpret_cast<bf16x8*>(la)     = pa0;
        *reinterpret_cast<bf16x8*>(la + 8) = pa1;
        *reinterpret_cast<bf16x8*>(lb)     = pb0;
        *reinterpret_cast<bf16x8*>(lb + 8) = pb1;

        __syncthreads();

        bf16x8 af[4], bf[4];
        const int kk = g * 8;
        #pragma unroll
        for (int m = 0; m < 4; ++m)
            af[m] = *reinterpret_cast<const bf16x8*>(As + (wr * 64 + m * 16 + l15) * 32 + kk);
        #pragma unroll
        for (int n = 0; n < 4; ++n)
            bf[n] = *reinterpret_cast<const bf16x8*>(Bs + (wc * 64 + n * 16 + l15) * 32 + kk);

        #pragma unroll
        for (int m = 0; m < 4; ++m)
            #pragma unroll
            for (int n = 0; n < 4; ++n)
                acc[m][n] = MFMA16(af[m], bf[n], acc[m][n]);
    }

    #pragma unroll
    for (int n = 0; n < 4; ++n) {
        const int e  = col0 + wc * 64 + n * 16 + l15;
        const float bv_ = bias[e];
        const int h = e >> 6, hd = e & 63;
        #pragma unroll
        for (int m = 0; m < 4; ++m) {
            #pragma unroll
            for (int j = 0; j < 4; ++j) {
                const int tok = row0 + wr * 64 + m * 16 + g * 4 + j;
                const int b = tok >> 11, s = tok & 2047;
                const int bh = b * 16 + h;
                Ob[((size_t)(bh * 2048 + s) << 6) | hd] =
                    (__bf16)((acc[m][n][j] + bv_) * oscale);
            }
        }
    }
}

// ---------------------------------------------------------------------------
// Kernel 2: V [bh][s][64] -> Vt [bh][64][s]
// ---------------------------------------------------------------------------
__global__ __launch_bounds__(256) void v_transpose(
    const __bf16* __restrict__ V, __bf16* __restrict__ Vt)
{
    __shared__ __align__(16) __bf16 T[64 * 72];
    const int t  = threadIdx.x;
    const int bh = blockIdx.y;
    const int s0 = blockIdx.x * 64;
    const int r  = t >> 2, q = t & 3;

    const __bf16* src = V + ((size_t)(bh * 2048 + s0 + r) << 6) + q * 16;
    bf16x8 v0 = *reinterpret_cast<const bf16x8*>(src);
    bf16x8 v1 = *reinterpret_cast<const bf16x8*>(src + 8);
    #pragma unroll
    for (int i = 0; i < 8; ++i) {
        T[(q * 16 + i) * 72 + r]     = v0[i];
        T[(q * 16 + 8 + i) * 72 + r] = v1[i];
    }
    __syncthreads();
    const int d = r, sc = q * 16;
    bf16x8 o0 = *reinterpret_cast<const bf16x8*>(&T[d * 72 + sc]);
    bf16x8 o1 = *reinterpret_cast<const bf16x8*>(&T[d * 72 + sc + 8]);
    __bf16* dst = Vt + ((size_t)(bh * 64 + d) << 11) + s0 + sc;
    *reinterpret_cast<bf16x8*>(dst)     = o0;
    *reinterpret_cast<bf16x8*>(dst + 8) = o1;
}

// ---------------------------------------------------------------------------
// Kernel 3: flash attention, swapped-QK^T 32x32 structure.
// Wave = 32 q rows; lane owns ONE q column (col = lane&31).
// S^T = mfma(K, Q): lane (q,hi) holds 32 of 64 P-values of its q.
// Softmax lane-local (+1 shfl_xor(32)); P -> PV B-operand via 16 packs +
// 8 permlane32_swap; PV computes ctx^T = mfma(Vt, P^T). No LDS at all.
// Q pre-scaled by 0.125*log2e -> exp2 domain; mask scaled by log2e at load.
// ---------------------------------------------------------------------------
__global__ __launch_bounds__(256) void flash_attn(
    const __bf16* __restrict__ Qb, const __bf16* __restrict__ Kb,
    const __bf16* __restrict__ Vt, const float* __restrict__ mask,
    float* __restrict__ out)
{
    // XCD-aware swizzle: 512 blocks, 64/XCD -> 4 heads per XCD's L2
    const int bid = blockIdx.y * 16 + blockIdx.x;
    const int wid = (bid & 7) * 64 + (bid >> 3);
    const int qt  = wid & 15;         // q-tile of 128 rows (4 waves * 32)
    const int bh  = wid >> 4;
    const int b = bh >> 4, h = bh & 15;

    const int t = threadIdx.x;
    const int lane = t & 63;
    const int w = t >> 6;
    const int l31 = lane & 31, hi = lane >> 5;
    const int q = (qt * 4 + w) * 32 + l31;     // this lane's q row

    // loop-invariant Q B-fragments: Q[q][ds*16 + hi*8 + 0..7]
    bf16x8 qf[4];
    {
        const __bf16* qp = Qb + ((size_t)(bh * 2048 + q) << 6) + hi * 8;
        #pragma unroll
        for (int ds = 0; ds < 4; ++ds)
            qf[ds] = *reinterpret_cast<const bf16x8*>(qp + ds * 16);
    }

    f32x16 ctx0 = f16zero(), ctx1 = f16zero();
    float mrow = -1e30f, lrow = 0.f;

    const float*  maskb = mask + b * 2048;
    const __bf16* Kbh = Kb + ((size_t)bh << 17);
    const __bf16* Vbh = Vt + ((size_t)bh << 17);

    for (int kt = 0; kt < 32; ++kt) {
        const int kbase = kt * 64;

        // ---- QK^T: S^T[k][q], two 32-k tiles, contraction d=64 in 4 slices
        f32x16 pt0 = f16zero(), pt1 = f16zero();
        #pragma unroll
        for (int ds = 0; ds < 4; ++ds) {
            bf16x8 k0 = *reinterpret_cast<const bf16x8*>(
                Kbh + ((size_t)(kbase + l31) << 6) + ds * 16 + hi * 8);
            bf16x8 k1 = *reinterpret_cast<const bf16x8*>(
                Kbh + ((size_t)(kbase + 32 + l31) << 6) + ds * 16 + hi * 8);
            pt0 = MFMA32(k0, qf[ds], pt0);
            pt1 = MFMA32(k1, qf[ds], pt1);
        }

        // ---- additive mask (per-key), scaled to log2 domain.
        // reg r = 4c+j -> k_local = j + 8c + 4hi
        #pragma unroll
        for (int c = 0; c < 4; ++c) {
            f32x4 mv0 = *reinterpret_cast<const f32x4*>(maskb + kbase + 4 * hi + 8 * c);
            f32x4 mv1 = *reinterpret_cast<const f32x4*>(maskb + kbase + 32 + 4 * hi + 8 * c);
            #pragma unroll
            for (int j = 0; j < 4; ++j) {
                pt0[4 * c + j] += mv0[j] * LOG2E;
                pt1[4 * c + j] += mv1[j] * LOG2E;
            }
        }

        // ---- lane-local softmax over this lane's 32 P-values
        float pmax = pt0[0];
        #pragma unroll
        for (int r = 1; r < 16; ++r) pmax = fmaxf(pmax, pt0[r]);
        #pragma unroll
        for (int r = 0; r < 16; ++r) pmax = fmaxf(pmax, pt1[r]);
        pmax = fmaxf(pmax, __shfl_xor(pmax, 32));   // other half of the k-tile

        // defer-max (T13): rescale only when max grew by > 8 (log2 domain)
        if (!__all(pmax <= mrow + 8.0f)) {
            const float mn = fmaxf(mrow, pmax);
            const float sf = exp2f(mrow - mn);
            mrow = mn;
            lrow *= sf;
            #pragma unroll
            for (int r = 0; r < 16; ++r) { ctx0[r] *= sf; ctx1[r] *= sf; }
        }

        float ps = 0.f;
        #pragma unroll
        for (int r = 0; r < 16; ++r) {
            float e = exp2f(pt0[r] - mrow);
            pt0[r] = e; ps += e;
        }
        #pragma unroll
        for (int r = 0; r < 16; ++r) {
            float e = exp2f(pt1[r] - mrow);
            pt1[r] = e; ps += e;
        }
        ps += __shfl_xor(ps, 32);
        lrow += ps;

        // ---- P^T -> PV B-operand (16 packs + 8 permlane32_swap), then PV.
        // dest frag ks words: w0,w1 from hi=0 lane, w2,w3 from hi=1 lane,
        // source regs r = 8*(ks&1) + 4*dh + 2m + b  (derivation verified).
        #pragma unroll
        for (int ks = 0; ks < 4; ++ks) {
            const f32x16& P = (ks < 2) ? pt0 : pt1;
            const int base = 8 * (ks & 1);
            unsigned a0 = pk2(P[base + 0], P[base + 1]);
            unsigned b0 = pk2(P[base + 4], P[base + 5]);
            unsigned a1 = pk2(P[base + 2], P[base + 3]);
            unsigned b1 = pk2(P[base + 6], P[base + 7]);
            plswap(a0, b0);   // -> w0 = a0, w2 = b0
            plswap(a1, b1);   // -> w1 = a1, w3 = b1
            u32x4 wv = {a0, a1, b0, b1};
            bf16x8 pb = __builtin_bit_cast(bf16x8, wv);

            bf16x8 v0 = *reinterpret_cast<const bf16x8*>(
                Vbh + ((size_t)l31 << 11) + kbase + ks * 16 + hi * 8);
            bf16x8 v1 = *reinterpret_cast<const bf16x8*>(
                Vbh + ((size_t)(32 + l31) << 11) + kbase + ks * 16 + hi * 8);
            ctx0 = MFMA32(v0, pb, ctx0);
            ctx1 = MFMA32(v1, pb, ctx1);
        }
    }

    // ---- epilogue: ctx^T C-layout -> out fp32 [b][s][h*64 + d]
    // reg r = 4c+j of tile h2 -> d = h2*32 + j + 8c + 4hi (j contiguous)
    const float inv = 1.0f / lrow;
    float* op = out + (((size_t)(b * 2048 + q)) << 10) + h * 64;
    #pragma unroll
    for (int c = 0; c < 4; ++c) {
        f32x4 s0v = {ctx0[4 * c + 0] * inv, ctx0[4 * c + 1] * inv,
                     ctx0[4 * c + 2] * inv, ctx0[4 * c + 3] * inv};
        f32x4 s1v = {ctx1[4 * c + 0] * inv, ctx1[4 * c + 1] * inv,
                     ctx1[4 * c + 2] * inv, ctx1[4 * c + 3] * inv};
        *reinterpret_cast<f32x4*>(op + 8 * c + 4 * hi)      = s0v;
        *reinterpret_cast<f32x4*>(op + 32 + 8 * c + 4 * hi) = s1v;
    }
}

// ---------------------------------------------------------------------------
extern "C" void kernel_launch(void* const* d_in, const int* in_sizes, int n_in,
                              void* d_out, int out_size, void* d_ws, size_t ws_size,
                              hipStream_t stream)
{
    const float* X    = (const float*)d_in[0];
    const float* mask = (const float*)d_in[1];
    const float* Wq   = (const float*)d_in[2];
    const float* bq   = (const float*)d_in[3];
    const float* Wk   = (const float*)d_in[4];
    const float* bk   = (const float*)d_in[5];
    const float* Wv   = (const float*)d_in[6];
    const float* bv   = (const float*)d_in[7];
    float* out = (float*)d_out;

    const size_t HEADS_ELEMS = (size_t)32 * 2048 * 64;
    __bf16* Qb = (__bf16*)d_ws;
    __bf16* Kb = Qb + HEADS_ELEMS;
    __bf16* Vb = Kb + HEADS_ELEMS;
    __bf16* Vt = Vb + HEADS_ELEMS;

    qkv_gemm<<<dim3(32, 8, 3), 256, 0, stream>>>(X, Wq, bq, Wk, bk, Wv, bv, Qb, Kb, Vb);
    v_transpose<<<dim3(32, 32), 256, 0, stream>>>(Vb, Vt);
    flash_attn<<<dim3(16, 32), 256, 0, stream>>>(Qb, Kb, Vt, mask, out);
}